// Round 6
// baseline (264.737 us; speedup 1.0000x reference)
//
#include <hip/hip_runtime.h>
#include <math.h>

#define B 2048
#define D 4096
#define C 1000
#define NNEG 16
#define EPS 1e-8f
#define NBLK (C + NNEG + B)

// ws layout:
//   float [0..B)          ce_part
//   float [B..B+C)        pos_sim
//   float [B+C..B+2C)     pos_cnt
//   float [B+2C..+NNEG)   neg_part
//   uint  [next]          counter   (memset to 0 each call, in-graph)
// All float slots fully written every call; counter reset by memset node.

__device__ __forceinline__ float wave_sum(float v) {
#pragma unroll
    for (int off = 32; off > 0; off >>= 1) v += __shfl_down(v, off, 64);
    return v;
}
__device__ __forceinline__ float wave_max(float v) {
#pragma unroll
    for (int off = 32; off > 0; off >>= 1) v = fmaxf(v, __shfl_down(v, off, 64));
    return v;
}

#define DOT16(u0, u1, u2, u3) \
    (u0.x * u0.x + u0.y * u0.y + u0.z * u0.z + u0.w * u0.w \
   + u1.x * u1.x + u1.y * u1.y + u1.z * u1.z + u1.w * u1.w \
   + u2.x * u2.x + u2.y * u2.y + u2.z * u2.z + u2.w * u2.w \
   + u3.x * u3.x + u3.y * u3.y + u3.z * u3.z + u3.w * u3.w)

#define FMA16(acc0, acc1, acc2, acc3, u0, u1, u2, u3, s) \
    acc0.x = fmaf(u0.x, s, acc0.x); acc0.y = fmaf(u0.y, s, acc0.y); \
    acc0.z = fmaf(u0.z, s, acc0.z); acc0.w = fmaf(u0.w, s, acc0.w); \
    acc1.x = fmaf(u1.x, s, acc1.x); acc1.y = fmaf(u1.y, s, acc1.y); \
    acc1.z = fmaf(u1.z, s, acc1.z); acc1.w = fmaf(u1.w, s, acc1.w); \
    acc2.x = fmaf(u2.x, s, acc2.x); acc2.y = fmaf(u2.y, s, acc2.y); \
    acc2.z = fmaf(u2.z, s, acc2.z); acc2.w = fmaf(u2.w, s, acc2.w); \
    acc3.x = fmaf(u3.x, s, acc3.x); acc3.y = fmaf(u3.y, s, acc3.y); \
    acc3.z = fmaf(u3.z, s, acc3.z); acc3.w = fmaf(u3.w, s, acc3.w);

// blocks [0,C): per-class pair-sim (pair-pipelined rows, skip n<2)
// blocks [C,C+NNEG): negative pairs (inline norms)
// blocks [C+NNEG,NBLK): cross-entropy rows
// last-arriving block runs the finalize reduction inline.
__global__ __launch_bounds__(256) void k_all(const float* __restrict__ xs,
                                             const float* __restrict__ yp,
                                             const int* __restrict__ yt,
                                             float* __restrict__ ce_part,
                                             float* __restrict__ pos_sim,
                                             float* __restrict__ pos_cnt,
                                             float* __restrict__ neg_part,
                                             unsigned* __restrict__ counter,
                                             float* __restrict__ out) {
    __shared__ float sbuf[12];
    const int lane = threadIdx.x & 63, wid = threadIdx.x >> 6;
    const int blk = blockIdx.x;

    if (blk < C) {
        // ---- per-class:  sum_{i<j in c} sim = (||S_c||^2 - n) / 2 ----
        const int cls = blk;
        __shared__ int match_idx[64];
        __shared__ int match_cnt;
        if (threadIdx.x == 0) match_cnt = 0;
        __syncthreads();
        for (int i = threadIdx.x; i < B; i += 256) {
            if (yt[i] == cls) {
                int p = atomicAdd(&match_cnt, 1);
                if (p < 64) match_idx[p] = i;
            }
        }
        __syncthreads();
        const int n = match_cnt < 64 ? match_cnt : 64;

        float psim = 0.0f;
        if (n >= 2) {
            float4 a0 = {0,0,0,0}, a1 = {0,0,0,0}, a2 = {0,0,0,0}, a3 = {0,0,0,0};
            int t = 0;
            for (; t + 2 <= n; t += 2) {
                const float4* rp = reinterpret_cast<const float4*>(xs + (size_t)match_idx[t] * D);
                const float4* rq = reinterpret_cast<const float4*>(xs + (size_t)match_idx[t + 1] * D);
                float4 p0 = rp[threadIdx.x];
                float4 p1 = rp[threadIdx.x + 256];
                float4 p2 = rp[threadIdx.x + 512];
                float4 p3 = rp[threadIdx.x + 768];
                float4 q0 = rq[threadIdx.x];
                float4 q1 = rq[threadIdx.x + 256];
                float4 q2 = rq[threadIdx.x + 512];
                float4 q3 = rq[threadIdx.x + 768];
                float ssp = DOT16(p0, p1, p2, p3);
                float ssq = DOT16(q0, q1, q2, q3);
                ssp = wave_sum(ssp);
                ssq = wave_sum(ssq);
                if (lane == 0) { sbuf[wid] = ssp; sbuf[4 + wid] = ssq; }
                __syncthreads();
                const float invp = 1.0f / fmaxf(sqrtf(sbuf[0] + sbuf[1] + sbuf[2] + sbuf[3]), EPS);
                const float invq = 1.0f / fmaxf(sqrtf(sbuf[4] + sbuf[5] + sbuf[6] + sbuf[7]), EPS);
                __syncthreads();  // sbuf reuse next iter
                FMA16(a0, a1, a2, a3, p0, p1, p2, p3, invp);
                FMA16(a0, a1, a2, a3, q0, q1, q2, q3, invq);
            }
            if (t < n) {
                const float4* rp = reinterpret_cast<const float4*>(xs + (size_t)match_idx[t] * D);
                float4 p0 = rp[threadIdx.x];
                float4 p1 = rp[threadIdx.x + 256];
                float4 p2 = rp[threadIdx.x + 512];
                float4 p3 = rp[threadIdx.x + 768];
                float ssp = DOT16(p0, p1, p2, p3);
                ssp = wave_sum(ssp);
                if (lane == 0) sbuf[wid] = ssp;
                __syncthreads();
                const float invp = 1.0f / fmaxf(sqrtf(sbuf[0] + sbuf[1] + sbuf[2] + sbuf[3]), EPS);
                __syncthreads();
                FMA16(a0, a1, a2, a3, p0, p1, p2, p3, invp);
            }
            float s2 = DOT16(a0, a1, a2, a3);
            s2 = wave_sum(s2);
            if (lane == 0) sbuf[wid] = s2;
            __syncthreads();
            if (threadIdx.x == 0) {
                float S2 = sbuf[0] + sbuf[1] + sbuf[2] + sbuf[3];
                psim = 0.5f * (S2 - (float)n);  // sum_i ||xn_i||^2 == n
            }
        }
        if (threadIdx.x == 0) {
            pos_sim[cls] = psim;
            pos_cnt[cls] = 0.5f * (float)n * (float)(n - 1);
        }
    } else if (blk < C + NNEG) {
        // ---- negative pair (0, j): inline norms + dot ----
        const int j = blk - C + 1;
        const float4* r0 = reinterpret_cast<const float4*>(xs);
        const float4* rj = reinterpret_cast<const float4*>(xs + (size_t)j * D);
        float ss0 = 0.0f, ssj = 0.0f, d = 0.0f;
#pragma unroll
        for (int k = 0; k < 4; ++k) {
            float4 a = r0[threadIdx.x + k * 256];
            float4 b = rj[threadIdx.x + k * 256];
            ss0 += a.x * a.x + a.y * a.y + a.z * a.z + a.w * a.w;
            ssj += b.x * b.x + b.y * b.y + b.z * b.z + b.w * b.w;
            d = fmaf(a.x, b.x, fmaf(a.y, b.y, fmaf(a.z, b.z, fmaf(a.w, b.w, d))));
        }
        ss0 = wave_sum(ss0);
        ssj = wave_sum(ssj);
        d = wave_sum(d);
        if (lane == 0) {
            sbuf[wid] = ss0;
            sbuf[4 + wid] = ssj;
            sbuf[8 + wid] = d;
        }
        __syncthreads();
        if (threadIdx.x == 0) {
            float n0 = fmaxf(sqrtf(sbuf[0] + sbuf[1] + sbuf[2] + sbuf[3]), EPS);
            float nj = fmaxf(sqrtf(sbuf[4] + sbuf[5] + sbuf[6] + sbuf[7]), EPS);
            float dot = sbuf[8] + sbuf[9] + sbuf[10] + sbuf[11];
            neg_part[j - 1] = fmaxf(0.0f, dot / (n0 * nj));
        }
    } else {
        // ---- cross-entropy row (250 float4) ----
        const int row = blk - C - NNEG;
        __shared__ float lds[C];
        const float4* r4 = reinterpret_cast<const float4*>(yp + (size_t)row * C);
        float4 v = {0.0f, 0.0f, 0.0f, 0.0f};
        float m = -INFINITY;
        if (threadIdx.x < 250) {
            v = r4[threadIdx.x];
            reinterpret_cast<float4*>(lds)[threadIdx.x] = v;
            m = fmaxf(fmaxf(v.x, v.y), fmaxf(v.z, v.w));
        }
        m = wave_max(m);
        if (lane == 0) sbuf[wid] = m;
        __syncthreads();
        m = fmaxf(fmaxf(sbuf[0], sbuf[1]), fmaxf(sbuf[2], sbuf[3]));
        float s = 0.0f;
        if (threadIdx.x < 250) {
            s = expf(v.x - m) + expf(v.y - m) + expf(v.z - m) + expf(v.w - m);
        }
        s = wave_sum(s);
        if (lane == 0) sbuf[4 + wid] = s;  // disjoint slots: no extra barrier
        __syncthreads();
        if (threadIdx.x == 0) {
            float tot = sbuf[4] + sbuf[5] + sbuf[6] + sbuf[7];
            ce_part[row] = logf(tot) + m - lds[yt[row]];
        }
    }

    // ---- completion detection + inline finalize (last block) ----
    // All partial stores above are by thread 0 -> its fence orders them.
    __shared__ unsigned s_old;
    __threadfence();
    if (threadIdx.x == 0) s_old = atomicAdd(counter, 1u);
    __syncthreads();
    if (s_old == (unsigned)(NBLK - 1)) {
        __threadfence();  // acquire: see all other blocks' stores
        float s_ce = 0.0f, s_sim = 0.0f, s_cnt = 0.0f;
        for (int i = threadIdx.x; i < B; i += 256) s_ce += ce_part[i];
        for (int i = threadIdx.x; i < C; i += 256) {
            s_sim += pos_sim[i];
            s_cnt += pos_cnt[i];
        }
        float s_neg = (threadIdx.x < NNEG) ? neg_part[threadIdx.x] : 0.0f;
        s_ce = wave_sum(s_ce);
        s_sim = wave_sum(s_sim);
        s_cnt = wave_sum(s_cnt);
        s_neg = wave_sum(s_neg);
        if (lane == 0) {
            sbuf[wid] = s_ce;
            sbuf[4 + wid] = s_sim;
            sbuf[8 + wid] = s_cnt;
        }
        __syncthreads();
        if (threadIdx.x == 0) {
            float ce = (sbuf[0] + sbuf[1] + sbuf[2] + sbuf[3]) / (float)B;
            float sim = sbuf[4] + sbuf[5] + sbuf[6] + sbuf[7];
            float cnt = sbuf[8] + sbuf[9] + sbuf[10] + sbuf[11];
            float pos = (cnt > 0.0f) ? (cnt - sim) / cnt : 0.0f;
            float neg = s_neg / (float)NNEG;  // wave 0 covers lanes 0..15
            out[0] = ce + pos + neg;
        }
    }
}

extern "C" void kernel_launch(void* const* d_in, const int* in_sizes, int n_in,
                              void* d_out, int out_size, void* d_ws, size_t ws_size,
                              hipStream_t stream) {
    const float* xs = (const float*)d_in[0];
    const float* yp = (const float*)d_in[1];
    const int* yt = (const int*)d_in[2];
    float* out = (float*)d_out;

    float* ce_part = (float*)d_ws;
    float* pos_sim = ce_part + B;
    float* pos_cnt = pos_sim + C;
    float* neg_part = pos_cnt + C;
    unsigned* counter = (unsigned*)(neg_part + NNEG);

    hipMemsetAsync(counter, 0, sizeof(unsigned), stream);
    k_all<<<NBLK, 256, 0, stream>>>(xs, yp, yt, ce_part, pos_sim, pos_cnt,
                                    neg_part, counter, out);
}

// Round 7
// 19.332 us; speedup vs baseline: 13.6946x; 13.6946x over previous
//
#include <hip/hip_runtime.h>
#include <math.h>

#define B 2048
#define D 4096
#define C 1000
#define NNEG 16
#define EPS 1e-8f

// ws layout (floats):
//   [0..B)           ce_part   (lse - target logit, per row)
//   [B..B+C)         pos_sim   (per-class pair-sim sum)
//   [B+C..B+2C)      pos_cnt   (per-class pair count)
//   [B+2C..+NNEG)    neg_part  (relu'd sim per pair)
// Every slot fully written every call -> no zeroing, no global atomics.

__device__ __forceinline__ float wave_sum(float v) {
#pragma unroll
    for (int off = 32; off > 0; off >>= 1) v += __shfl_down(v, off, 64);
    return v;
}
__device__ __forceinline__ float wave_max(float v) {
#pragma unroll
    for (int off = 32; off > 0; off >>= 1) v = fmaxf(v, __shfl_down(v, off, 64));
    return v;
}

#define SUMSQ16(u0, u1, u2, u3) \
    (u0.x * u0.x + u0.y * u0.y + u0.z * u0.z + u0.w * u0.w \
   + u1.x * u1.x + u1.y * u1.y + u1.z * u1.z + u1.w * u1.w \
   + u2.x * u2.x + u2.y * u2.y + u2.z * u2.z + u2.w * u2.w \
   + u3.x * u3.x + u3.y * u3.y + u3.z * u3.z + u3.w * u3.w)

#define FMA16(acc0, acc1, acc2, acc3, u0, u1, u2, u3, s) \
    acc0.x = fmaf(u0.x, s, acc0.x); acc0.y = fmaf(u0.y, s, acc0.y); \
    acc0.z = fmaf(u0.z, s, acc0.z); acc0.w = fmaf(u0.w, s, acc0.w); \
    acc1.x = fmaf(u1.x, s, acc1.x); acc1.y = fmaf(u1.y, s, acc1.y); \
    acc1.z = fmaf(u1.z, s, acc1.z); acc1.w = fmaf(u1.w, s, acc1.w); \
    acc2.x = fmaf(u2.x, s, acc2.x); acc2.y = fmaf(u2.y, s, acc2.y); \
    acc2.z = fmaf(u2.z, s, acc2.z); acc2.w = fmaf(u2.w, s, acc2.w); \
    acc3.x = fmaf(u3.x, s, acc3.x); acc3.y = fmaf(u3.y, s, acc3.y); \
    acc3.z = fmaf(u3.z, s, acc3.z); acc3.w = fmaf(u3.w, s, acc3.w);

// Fused: blocks [0,C) per-class pair-sim; [C,C+NNEG) negative pairs;
//        [C+NNEG, ...) cross-entropy rows. xs read at most once.
__global__ __launch_bounds__(256) void k_main(const float* __restrict__ xs,
                                              const float* __restrict__ yp,
                                              const int* __restrict__ yt,
                                              float* __restrict__ ce_part,
                                              float* __restrict__ pos_sim,
                                              float* __restrict__ pos_cnt,
                                              float* __restrict__ neg_part) {
    __shared__ float sbuf[12];
    const int lane = threadIdx.x & 63, wid = threadIdx.x >> 6;
    const int blk = blockIdx.x;

    if (blk < C) {
        // ---- per-class:  sum_{i<j in c} sim = (||S_c||^2 - n) / 2 ----
        const int cls = blk;
        __shared__ int match_idx[64];
        __shared__ int match_cnt;
        if (threadIdx.x == 0) match_cnt = 0;
        __syncthreads();
        for (int i = threadIdx.x; i < B; i += 256) {
            if (yt[i] == cls) {
                int p = atomicAdd(&match_cnt, 1);
                if (p < 64) match_idx[p] = i;
            }
        }
        __syncthreads();
        const int n = match_cnt < 64 ? match_cnt : 64;

        float psim = 0.0f;
        if (n >= 2) {
            // pair-pipelined: 2 rows (8 float4 loads) in flight per iteration
            float4 a0 = {0,0,0,0}, a1 = {0,0,0,0}, a2 = {0,0,0,0}, a3 = {0,0,0,0};
            int t = 0;
            for (; t + 2 <= n; t += 2) {
                const float4* rp = reinterpret_cast<const float4*>(xs + (size_t)match_idx[t] * D);
                const float4* rq = reinterpret_cast<const float4*>(xs + (size_t)match_idx[t + 1] * D);
                float4 p0 = rp[threadIdx.x];
                float4 p1 = rp[threadIdx.x + 256];
                float4 p2 = rp[threadIdx.x + 512];
                float4 p3 = rp[threadIdx.x + 768];
                float4 q0 = rq[threadIdx.x];
                float4 q1 = rq[threadIdx.x + 256];
                float4 q2 = rq[threadIdx.x + 512];
                float4 q3 = rq[threadIdx.x + 768];
                float ssp = SUMSQ16(p0, p1, p2, p3);
                float ssq = SUMSQ16(q0, q1, q2, q3);
                ssp = wave_sum(ssp);
                ssq = wave_sum(ssq);
                if (lane == 0) { sbuf[wid] = ssp; sbuf[4 + wid] = ssq; }
                __syncthreads();
                const float invp = 1.0f / fmaxf(sqrtf(sbuf[0] + sbuf[1] + sbuf[2] + sbuf[3]), EPS);
                const float invq = 1.0f / fmaxf(sqrtf(sbuf[4] + sbuf[5] + sbuf[6] + sbuf[7]), EPS);
                __syncthreads();  // sbuf reused next iteration
                FMA16(a0, a1, a2, a3, p0, p1, p2, p3, invp);
                FMA16(a0, a1, a2, a3, q0, q1, q2, q3, invq);
            }
            if (t < n) {
                const float4* rp = reinterpret_cast<const float4*>(xs + (size_t)match_idx[t] * D);
                float4 p0 = rp[threadIdx.x];
                float4 p1 = rp[threadIdx.x + 256];
                float4 p2 = rp[threadIdx.x + 512];
                float4 p3 = rp[threadIdx.x + 768];
                float ssp = SUMSQ16(p0, p1, p2, p3);
                ssp = wave_sum(ssp);
                if (lane == 0) sbuf[wid] = ssp;
                __syncthreads();
                const float invp = 1.0f / fmaxf(sqrtf(sbuf[0] + sbuf[1] + sbuf[2] + sbuf[3]), EPS);
                __syncthreads();
                FMA16(a0, a1, a2, a3, p0, p1, p2, p3, invp);
            }
            float s2 = SUMSQ16(a0, a1, a2, a3);
            s2 = wave_sum(s2);
            if (lane == 0) sbuf[wid] = s2;
            __syncthreads();
            if (threadIdx.x == 0) {
                float S2 = sbuf[0] + sbuf[1] + sbuf[2] + sbuf[3];
                psim = 0.5f * (S2 - (float)n);  // sum_i ||xn_i||^2 == n
            }
        }
        if (threadIdx.x == 0) {
            pos_sim[cls] = psim;
            pos_cnt[cls] = 0.5f * (float)n * (float)(n - 1);
        }
    } else if (blk < C + NNEG) {
        // ---- negative pair (0, j), inline norms ----
        const int j = blk - C + 1;
        const float4* r0 = reinterpret_cast<const float4*>(xs);
        const float4* rj = reinterpret_cast<const float4*>(xs + (size_t)j * D);
        float ss0 = 0.0f, ssj = 0.0f, d = 0.0f;
#pragma unroll
        for (int k = 0; k < 4; ++k) {
            float4 a = r0[threadIdx.x + k * 256];
            float4 b = rj[threadIdx.x + k * 256];
            ss0 += a.x * a.x + a.y * a.y + a.z * a.z + a.w * a.w;
            ssj += b.x * b.x + b.y * b.y + b.z * b.z + b.w * b.w;
            d = fmaf(a.x, b.x, fmaf(a.y, b.y, fmaf(a.z, b.z, fmaf(a.w, b.w, d))));
        }
        ss0 = wave_sum(ss0);
        ssj = wave_sum(ssj);
        d = wave_sum(d);
        if (lane == 0) {
            sbuf[wid] = ss0;
            sbuf[4 + wid] = ssj;
            sbuf[8 + wid] = d;
        }
        __syncthreads();
        if (threadIdx.x == 0) {
            float n0 = fmaxf(sqrtf(sbuf[0] + sbuf[1] + sbuf[2] + sbuf[3]), EPS);
            float nj = fmaxf(sqrtf(sbuf[4] + sbuf[5] + sbuf[6] + sbuf[7]), EPS);
            float dot = sbuf[8] + sbuf[9] + sbuf[10] + sbuf[11];
            neg_part[j - 1] = fmaxf(0.0f, dot / (n0 * nj));
        }
    } else {
        // ---- cross-entropy row (float4 loads: C = 250 float4) ----
        const int row = blk - C - NNEG;
        __shared__ float lds[C];
        const float4* r4 = reinterpret_cast<const float4*>(yp + (size_t)row * C);
        float4 v = {0.0f, 0.0f, 0.0f, 0.0f};
        float m = -INFINITY;
        if (threadIdx.x < 250) {
            v = r4[threadIdx.x];
            reinterpret_cast<float4*>(lds)[threadIdx.x] = v;
            m = fmaxf(fmaxf(v.x, v.y), fmaxf(v.z, v.w));
        }
        m = wave_max(m);
        if (lane == 0) sbuf[wid] = m;
        __syncthreads();
        m = fmaxf(fmaxf(sbuf[0], sbuf[1]), fmaxf(sbuf[2], sbuf[3]));
        float s = 0.0f;
        if (threadIdx.x < 250) {
            s = expf(v.x - m) + expf(v.y - m) + expf(v.z - m) + expf(v.w - m);
        }
        s = wave_sum(s);
        if (lane == 0) sbuf[4 + wid] = s;  // disjoint slots: no extra barrier
        __syncthreads();
        if (threadIdx.x == 0) {
            float tot = sbuf[4] + sbuf[5] + sbuf[6] + sbuf[7];
            ce_part[row] = logf(tot) + m - lds[yt[row]];
        }
    }
}

__global__ __launch_bounds__(256) void k_finalize(const float* __restrict__ ce_part,
                                                  const float* __restrict__ pos_sim,
                                                  const float* __restrict__ pos_cnt,
                                                  const float* __restrict__ neg_part,
                                                  float* __restrict__ out) {
    __shared__ float sbuf[12];
    const int lane = threadIdx.x & 63, wid = threadIdx.x >> 6;
    float s_ce = 0.0f, s_sim = 0.0f, s_cnt = 0.0f;
    for (int i = threadIdx.x; i < B; i += 256) s_ce += ce_part[i];
    for (int i = threadIdx.x; i < C; i += 256) {
        s_sim += pos_sim[i];
        s_cnt += pos_cnt[i];
    }
    float s_neg = (threadIdx.x < NNEG) ? neg_part[threadIdx.x] : 0.0f;
    s_ce = wave_sum(s_ce);
    s_sim = wave_sum(s_sim);
    s_cnt = wave_sum(s_cnt);
    s_neg = wave_sum(s_neg);
    if (lane == 0) {
        sbuf[wid] = s_ce;
        sbuf[4 + wid] = s_sim;
        sbuf[8 + wid] = s_cnt;
    }
    __syncthreads();
    if (threadIdx.x == 0) {
        float ce = (sbuf[0] + sbuf[1] + sbuf[2] + sbuf[3]) / (float)B;
        float sim = sbuf[4] + sbuf[5] + sbuf[6] + sbuf[7];
        float cnt = sbuf[8] + sbuf[9] + sbuf[10] + sbuf[11];
        float pos = (cnt > 0.0f) ? (cnt - sim) / cnt : 0.0f;
        float neg = s_neg / (float)NNEG;  // wave 0 covers lanes 0..15
        out[0] = ce + pos + neg;
    }
}

extern "C" void kernel_launch(void* const* d_in, const int* in_sizes, int n_in,
                              void* d_out, int out_size, void* d_ws, size_t ws_size,
                              hipStream_t stream) {
    const float* xs = (const float*)d_in[0];
    const float* yp = (const float*)d_in[1];
    const int* yt = (const int*)d_in[2];
    float* out = (float*)d_out;

    float* ce_part = (float*)d_ws;
    float* pos_sim = ce_part + B;
    float* pos_cnt = pos_sim + C;
    float* neg_part = pos_cnt + C;

    k_main<<<C + NNEG + B, 256, 0, stream>>>(xs, yp, yt, ce_part, pos_sim, pos_cnt, neg_part);
    k_finalize<<<1, 256, 0, stream>>>(ce_part, pos_sim, pos_cnt, neg_part, out);
}

// Round 8
// 18.808 us; speedup vs baseline: 14.0757x; 1.0278x over previous
//
#include <hip/hip_runtime.h>
#include <math.h>

#define B 2048
#define D 4096
#define C 1000
#define NNEG 16
#define EPS 1e-8f

// ws layout (floats):
//   [0..B)           ce_part   (lse - target logit, per row)
//   [B..B+C)         pos_sim   (per-class pair-sim sum)
//   [B+C..B+2C)      pos_cnt   (per-class pair count)
//   [B+2C..+NNEG)    neg_part  (relu'd sim per pair)
// Every slot fully written every call -> no zeroing, no global atomics.

__device__ __forceinline__ float wave_sum(float v) {
#pragma unroll
    for (int off = 32; off > 0; off >>= 1) v += __shfl_down(v, off, 64);
    return v;
}
__device__ __forceinline__ float wave_max(float v) {
#pragma unroll
    for (int off = 32; off > 0; off >>= 1) v = fmaxf(v, __shfl_down(v, off, 64));
    return v;
}

#define SUMSQ16(u0, u1, u2, u3) \
    (u0.x * u0.x + u0.y * u0.y + u0.z * u0.z + u0.w * u0.w \
   + u1.x * u1.x + u1.y * u1.y + u1.z * u1.z + u1.w * u1.w \
   + u2.x * u2.x + u2.y * u2.y + u2.z * u2.z + u2.w * u2.w \
   + u3.x * u3.x + u3.y * u3.y + u3.z * u3.z + u3.w * u3.w)

#define FMA16(acc0, acc1, acc2, acc3, u0, u1, u2, u3, s) \
    acc0.x = fmaf(u0.x, s, acc0.x); acc0.y = fmaf(u0.y, s, acc0.y); \
    acc0.z = fmaf(u0.z, s, acc0.z); acc0.w = fmaf(u0.w, s, acc0.w); \
    acc1.x = fmaf(u1.x, s, acc1.x); acc1.y = fmaf(u1.y, s, acc1.y); \
    acc1.z = fmaf(u1.z, s, acc1.z); acc1.w = fmaf(u1.w, s, acc1.w); \
    acc2.x = fmaf(u2.x, s, acc2.x); acc2.y = fmaf(u2.y, s, acc2.y); \
    acc2.z = fmaf(u2.z, s, acc2.z); acc2.w = fmaf(u2.w, s, acc2.w); \
    acc3.x = fmaf(u3.x, s, acc3.x); acc3.y = fmaf(u3.y, s, acc3.y); \
    acc3.z = fmaf(u3.z, s, acc3.z); acc3.w = fmaf(u3.w, s, acc3.w);

#define LOAD16(dst0, dst1, dst2, dst3, ptr) \
    dst0 = ptr[threadIdx.x];       dst1 = ptr[threadIdx.x + 256]; \
    dst2 = ptr[threadIdx.x + 512]; dst3 = ptr[threadIdx.x + 768];

// Fused: blocks [0,C) per-class pair-sim; [C,C+NNEG) negative pairs;
//        [C+NNEG, ...) cross-entropy rows. xs read at most once.
__global__ __launch_bounds__(256) void k_main(const float* __restrict__ xs,
                                              const float* __restrict__ yp,
                                              const int* __restrict__ yt,
                                              float* __restrict__ ce_part,
                                              float* __restrict__ pos_sim,
                                              float* __restrict__ pos_cnt,
                                              float* __restrict__ neg_part) {
    __shared__ float sbuf[13];
    const int lane = threadIdx.x & 63, wid = threadIdx.x >> 6;
    const int blk = blockIdx.x;

    if (blk < C) {
        // ---- per-class:  sum_{i<j in c} sim = (||S_c||^2 - n) / 2 ----
        const int cls = blk;
        __shared__ int match_idx[64];
        __shared__ int match_cnt;
        if (threadIdx.x == 0) match_cnt = 0;
        __syncthreads();
        for (int i = threadIdx.x; i < B; i += 256) {
            if (yt[i] == cls) {
                int p = atomicAdd(&match_cnt, 1);
                if (p < 64) match_idx[p] = i;
            }
        }
        __syncthreads();
        const int n = match_cnt < 64 ? match_cnt : 64;

        float psim = 0.0f;
        if (n >= 2) {
            // 3-row pipeline: 12 float4 loads in flight per iteration
            float4 a0 = {0,0,0,0}, a1 = {0,0,0,0}, a2 = {0,0,0,0}, a3 = {0,0,0,0};
            int t = 0;
            for (; t + 3 <= n; t += 3) {
                const float4* rp = reinterpret_cast<const float4*>(xs + (size_t)match_idx[t] * D);
                const float4* rq = reinterpret_cast<const float4*>(xs + (size_t)match_idx[t + 1] * D);
                const float4* rr = reinterpret_cast<const float4*>(xs + (size_t)match_idx[t + 2] * D);
                float4 p0, p1, p2, p3, q0, q1, q2, q3, w0, w1, w2, w3;
                LOAD16(p0, p1, p2, p3, rp);
                LOAD16(q0, q1, q2, q3, rq);
                LOAD16(w0, w1, w2, w3, rr);
                float ssp = SUMSQ16(p0, p1, p2, p3);
                float ssq = SUMSQ16(q0, q1, q2, q3);
                float ssw = SUMSQ16(w0, w1, w2, w3);
                ssp = wave_sum(ssp);
                ssq = wave_sum(ssq);
                ssw = wave_sum(ssw);
                if (lane == 0) { sbuf[wid] = ssp; sbuf[4 + wid] = ssq; sbuf[8 + wid] = ssw; }
                __syncthreads();
                const float invp = 1.0f / fmaxf(sqrtf(sbuf[0] + sbuf[1] + sbuf[2] + sbuf[3]), EPS);
                const float invq = 1.0f / fmaxf(sqrtf(sbuf[4] + sbuf[5] + sbuf[6] + sbuf[7]), EPS);
                const float invw = 1.0f / fmaxf(sqrtf(sbuf[8] + sbuf[9] + sbuf[10] + sbuf[11]), EPS);
                __syncthreads();  // sbuf reused next iteration
                FMA16(a0, a1, a2, a3, p0, p1, p2, p3, invp);
                FMA16(a0, a1, a2, a3, q0, q1, q2, q3, invq);
                FMA16(a0, a1, a2, a3, w0, w1, w2, w3, invw);
            }
            const int rem = n - t;
            if (rem == 2) {
                const float4* rp = reinterpret_cast<const float4*>(xs + (size_t)match_idx[t] * D);
                const float4* rq = reinterpret_cast<const float4*>(xs + (size_t)match_idx[t + 1] * D);
                float4 p0, p1, p2, p3, q0, q1, q2, q3;
                LOAD16(p0, p1, p2, p3, rp);
                LOAD16(q0, q1, q2, q3, rq);
                float ssp = SUMSQ16(p0, p1, p2, p3);
                float ssq = SUMSQ16(q0, q1, q2, q3);
                ssp = wave_sum(ssp);
                ssq = wave_sum(ssq);
                if (lane == 0) { sbuf[wid] = ssp; sbuf[4 + wid] = ssq; }
                __syncthreads();
                const float invp = 1.0f / fmaxf(sqrtf(sbuf[0] + sbuf[1] + sbuf[2] + sbuf[3]), EPS);
                const float invq = 1.0f / fmaxf(sqrtf(sbuf[4] + sbuf[5] + sbuf[6] + sbuf[7]), EPS);
                __syncthreads();
                FMA16(a0, a1, a2, a3, p0, p1, p2, p3, invp);
                FMA16(a0, a1, a2, a3, q0, q1, q2, q3, invq);
            } else if (rem == 1) {
                const float4* rp = reinterpret_cast<const float4*>(xs + (size_t)match_idx[t] * D);
                float4 p0, p1, p2, p3;
                LOAD16(p0, p1, p2, p3, rp);
                float ssp = SUMSQ16(p0, p1, p2, p3);
                ssp = wave_sum(ssp);
                if (lane == 0) sbuf[wid] = ssp;
                __syncthreads();
                const float invp = 1.0f / fmaxf(sqrtf(sbuf[0] + sbuf[1] + sbuf[2] + sbuf[3]), EPS);
                __syncthreads();
                FMA16(a0, a1, a2, a3, p0, p1, p2, p3, invp);
            }
            float s2 = SUMSQ16(a0, a1, a2, a3);
            s2 = wave_sum(s2);
            if (lane == 0) sbuf[wid] = s2;
            __syncthreads();
            if (threadIdx.x == 0) {
                float S2 = sbuf[0] + sbuf[1] + sbuf[2] + sbuf[3];
                psim = 0.5f * (S2 - (float)n);  // sum_i ||xn_i||^2 == n
            }
        }
        if (threadIdx.x == 0) {
            pos_sim[cls] = psim;
            pos_cnt[cls] = 0.5f * (float)n * (float)(n - 1);
        }
    } else if (blk < C + NNEG) {
        // ---- negative pair (0, j), inline norms ----
        const int j = blk - C + 1;
        const float4* r0 = reinterpret_cast<const float4*>(xs);
        const float4* rj = reinterpret_cast<const float4*>(xs + (size_t)j * D);
        float ss0 = 0.0f, ssj = 0.0f, d = 0.0f;
#pragma unroll
        for (int k = 0; k < 4; ++k) {
            float4 a = r0[threadIdx.x + k * 256];
            float4 b = rj[threadIdx.x + k * 256];
            ss0 += a.x * a.x + a.y * a.y + a.z * a.z + a.w * a.w;
            ssj += b.x * b.x + b.y * b.y + b.z * b.z + b.w * b.w;
            d = fmaf(a.x, b.x, fmaf(a.y, b.y, fmaf(a.z, b.z, fmaf(a.w, b.w, d))));
        }
        ss0 = wave_sum(ss0);
        ssj = wave_sum(ssj);
        d = wave_sum(d);
        if (lane == 0) {
            sbuf[wid] = ss0;
            sbuf[4 + wid] = ssj;
            sbuf[8 + wid] = d;
        }
        __syncthreads();
        if (threadIdx.x == 0) {
            float n0 = fmaxf(sqrtf(sbuf[0] + sbuf[1] + sbuf[2] + sbuf[3]), EPS);
            float nj = fmaxf(sqrtf(sbuf[4] + sbuf[5] + sbuf[6] + sbuf[7]), EPS);
            float dot = sbuf[8] + sbuf[9] + sbuf[10] + sbuf[11];
            neg_part[j - 1] = fmaxf(0.0f, dot / (n0 * nj));
        }
    } else {
        // ---- cross-entropy row (250 float4 loads, target logit extracted
        //      directly from the owning thread's registers — no LDS row) ----
        const int row = blk - C - NNEG;
        const float4* r4 = reinterpret_cast<const float4*>(yp + (size_t)row * C);
        const int tgt = yt[row];
        float4 v = {0.0f, 0.0f, 0.0f, 0.0f};
        float m = -INFINITY;
        if (threadIdx.x < 250) {
            v = r4[threadIdx.x];
            m = fmaxf(fmaxf(v.x, v.y), fmaxf(v.z, v.w));
        }
        if (threadIdx.x == (tgt >> 2)) {
            const int c4 = tgt & 3;
            sbuf[12] = (c4 == 0) ? v.x : (c4 == 1) ? v.y : (c4 == 2) ? v.z : v.w;
        }
        m = wave_max(m);
        if (lane == 0) sbuf[wid] = m;
        __syncthreads();
        m = fmaxf(fmaxf(sbuf[0], sbuf[1]), fmaxf(sbuf[2], sbuf[3]));
        float s = 0.0f;
        if (threadIdx.x < 250) {
            s = expf(v.x - m) + expf(v.y - m) + expf(v.z - m) + expf(v.w - m);
        }
        s = wave_sum(s);
        if (lane == 0) sbuf[4 + wid] = s;  // disjoint slots: no extra barrier
        __syncthreads();
        if (threadIdx.x == 0) {
            float tot = sbuf[4] + sbuf[5] + sbuf[6] + sbuf[7];
            ce_part[row] = logf(tot) + m - sbuf[12];
        }
    }
}

__global__ __launch_bounds__(256) void k_finalize(const float* __restrict__ ce_part,
                                                  const float* __restrict__ pos_sim,
                                                  const float* __restrict__ pos_cnt,
                                                  const float* __restrict__ neg_part,
                                                  float* __restrict__ out) {
    __shared__ float sbuf[12];
    const int lane = threadIdx.x & 63, wid = threadIdx.x >> 6;
    float s_ce = 0.0f, s_sim = 0.0f, s_cnt = 0.0f;
    for (int i = threadIdx.x; i < B; i += 256) s_ce += ce_part[i];
    for (int i = threadIdx.x; i < C; i += 256) {
        s_sim += pos_sim[i];
        s_cnt += pos_cnt[i];
    }
    float s_neg = (threadIdx.x < NNEG) ? neg_part[threadIdx.x] : 0.0f;
    s_ce = wave_sum(s_ce);
    s_sim = wave_sum(s_sim);
    s_cnt = wave_sum(s_cnt);
    s_neg = wave_sum(s_neg);
    if (lane == 0) {
        sbuf[wid] = s_ce;
        sbuf[4 + wid] = s_sim;
        sbuf[8 + wid] = s_cnt;
    }
    __syncthreads();
    if (threadIdx.x == 0) {
        float ce = (sbuf[0] + sbuf[1] + sbuf[2] + sbuf[3]) / (float)B;
        float sim = sbuf[4] + sbuf[5] + sbuf[6] + sbuf[7];
        float cnt = sbuf[8] + sbuf[9] + sbuf[10] + sbuf[11];
        float pos = (cnt > 0.0f) ? (cnt - sim) / cnt : 0.0f;
        float neg = s_neg / (float)NNEG;  // wave 0 covers lanes 0..15
        out[0] = ce + pos + neg;
    }
}

extern "C" void kernel_launch(void* const* d_in, const int* in_sizes, int n_in,
                              void* d_out, int out_size, void* d_ws, size_t ws_size,
                              hipStream_t stream) {
    const float* xs = (const float*)d_in[0];
    const float* yp = (const float*)d_in[1];
    const int* yt = (const int*)d_in[2];
    float* out = (float*)d_out;

    float* ce_part = (float*)d_ws;
    float* pos_sim = ce_part + B;
    float* pos_cnt = pos_sim + C;
    float* neg_part = pos_cnt + C;

    k_main<<<C + NNEG + B, 256, 0, stream>>>(xs, yp, yt, ce_part, pos_sim, pos_cnt, neg_part);
    k_finalize<<<1, 256, 0, stream>>>(ce_part, pos_sim, pos_cnt, neg_part, out);
}

// Round 9
// 16.415 us; speedup vs baseline: 16.1279x; 1.1458x over previous
//
#include <hip/hip_runtime.h>
#include <math.h>

#define B 2048
#define D 4096
#define C 1000
#define NNEG 16
#define EPS 1e-8f

// ws layout (floats):
//   [0..B)           ce_part   (lse - target logit, per row)
//   [B..B+C)         pos_sim   (per-class pair-sim sum)
//   [B+C..B+2C)      pos_cnt   (per-class pair count)
//   [B+2C..+NNEG)    neg_part  (relu'd sim per pair)
// Every slot fully written every call -> no zeroing, no global atomics.

__device__ __forceinline__ float wave_sum(float v) {
#pragma unroll
    for (int off = 32; off > 0; off >>= 1) v += __shfl_down(v, off, 64);
    return v;
}
__device__ __forceinline__ float wave_max(float v) {
#pragma unroll
    for (int off = 32; off > 0; off >>= 1) v = fmaxf(v, __shfl_down(v, off, 64));
    return v;
}

#define SUMSQ16(u0, u1, u2, u3) \
    (u0.x * u0.x + u0.y * u0.y + u0.z * u0.z + u0.w * u0.w \
   + u1.x * u1.x + u1.y * u1.y + u1.z * u1.z + u1.w * u1.w \
   + u2.x * u2.x + u2.y * u2.y + u2.z * u2.z + u2.w * u2.w \
   + u3.x * u3.x + u3.y * u3.y + u3.z * u3.z + u3.w * u3.w)

#define FMA16(acc0, acc1, acc2, acc3, u0, u1, u2, u3, s) \
    acc0.x = fmaf(u0.x, s, acc0.x); acc0.y = fmaf(u0.y, s, acc0.y); \
    acc0.z = fmaf(u0.z, s, acc0.z); acc0.w = fmaf(u0.w, s, acc0.w); \
    acc1.x = fmaf(u1.x, s, acc1.x); acc1.y = fmaf(u1.y, s, acc1.y); \
    acc1.z = fmaf(u1.z, s, acc1.z); acc1.w = fmaf(u1.w, s, acc1.w); \
    acc2.x = fmaf(u2.x, s, acc2.x); acc2.y = fmaf(u2.y, s, acc2.y); \
    acc2.z = fmaf(u2.z, s, acc2.z); acc2.w = fmaf(u2.w, s, acc2.w); \
    acc3.x = fmaf(u3.x, s, acc3.x); acc3.y = fmaf(u3.y, s, acc3.y); \
    acc3.z = fmaf(u3.z, s, acc3.z); acc3.w = fmaf(u3.w, s, acc3.w);

#define LOAD16(dst0, dst1, dst2, dst3, ptr) \
    dst0 = ptr[threadIdx.x];       dst1 = ptr[threadIdx.x + 256]; \
    dst2 = ptr[threadIdx.x + 512]; dst3 = ptr[threadIdx.x + 768];

// Fused: blocks [0,C) per-class pair-sim; [C,C+NNEG) negative pairs;
//        [C+NNEG, ...) cross-entropy rows. xs read at most once.
// Class blocks (the long poles) dispatch first so their tails hide
// under the CE stream.
__global__ __launch_bounds__(256) void k_main(const float* __restrict__ xs,
                                              const float* __restrict__ yp,
                                              const int* __restrict__ yt,
                                              float* __restrict__ ce_part,
                                              float* __restrict__ pos_sim,
                                              float* __restrict__ pos_cnt,
                                              float* __restrict__ neg_part) {
    __shared__ float sbuf[13];
    const int lane = threadIdx.x & 63, wid = threadIdx.x >> 6;
    const int blk = blockIdx.x;

    if (blk < C) {
        // ---- per-class:  sum_{i<j in c} sim = (||S_c||^2 - n) / 2 ----
        const int cls = blk;
        __shared__ int match_idx[64];
        __shared__ int match_cnt;
        if (threadIdx.x == 0) match_cnt = 0;
        __syncthreads();
        for (int i = threadIdx.x; i < B; i += 256) {
            if (yt[i] == cls) {
                int p = atomicAdd(&match_cnt, 1);
                if (p < 64) match_idx[p] = i;
            }
        }
        __syncthreads();
        const int n = match_cnt < 64 ? match_cnt : 64;

        float psim = 0.0f;
        if (n >= 2) {
            // 3-row pipeline: 12 float4 loads in flight per iteration
            float4 a0 = {0,0,0,0}, a1 = {0,0,0,0}, a2 = {0,0,0,0}, a3 = {0,0,0,0};
            int t = 0;
            for (; t + 3 <= n; t += 3) {
                const float4* rp = reinterpret_cast<const float4*>(xs + (size_t)match_idx[t] * D);
                const float4* rq = reinterpret_cast<const float4*>(xs + (size_t)match_idx[t + 1] * D);
                const float4* rr = reinterpret_cast<const float4*>(xs + (size_t)match_idx[t + 2] * D);
                float4 p0, p1, p2, p3, q0, q1, q2, q3, w0, w1, w2, w3;
                LOAD16(p0, p1, p2, p3, rp);
                LOAD16(q0, q1, q2, q3, rq);
                LOAD16(w0, w1, w2, w3, rr);
                float ssp = SUMSQ16(p0, p1, p2, p3);
                float ssq = SUMSQ16(q0, q1, q2, q3);
                float ssw = SUMSQ16(w0, w1, w2, w3);
                ssp = wave_sum(ssp);
                ssq = wave_sum(ssq);
                ssw = wave_sum(ssw);
                if (lane == 0) { sbuf[wid] = ssp; sbuf[4 + wid] = ssq; sbuf[8 + wid] = ssw; }
                __syncthreads();
                const float invp = 1.0f / fmaxf(sqrtf(sbuf[0] + sbuf[1] + sbuf[2] + sbuf[3]), EPS);
                const float invq = 1.0f / fmaxf(sqrtf(sbuf[4] + sbuf[5] + sbuf[6] + sbuf[7]), EPS);
                const float invw = 1.0f / fmaxf(sqrtf(sbuf[8] + sbuf[9] + sbuf[10] + sbuf[11]), EPS);
                __syncthreads();  // sbuf reused next iteration
                FMA16(a0, a1, a2, a3, p0, p1, p2, p3, invp);
                FMA16(a0, a1, a2, a3, q0, q1, q2, q3, invq);
                FMA16(a0, a1, a2, a3, w0, w1, w2, w3, invw);
            }
            const int rem = n - t;
            if (rem == 2) {
                const float4* rp = reinterpret_cast<const float4*>(xs + (size_t)match_idx[t] * D);
                const float4* rq = reinterpret_cast<const float4*>(xs + (size_t)match_idx[t + 1] * D);
                float4 p0, p1, p2, p3, q0, q1, q2, q3;
                LOAD16(p0, p1, p2, p3, rp);
                LOAD16(q0, q1, q2, q3, rq);
                float ssp = SUMSQ16(p0, p1, p2, p3);
                float ssq = SUMSQ16(q0, q1, q2, q3);
                ssp = wave_sum(ssp);
                ssq = wave_sum(ssq);
                if (lane == 0) { sbuf[wid] = ssp; sbuf[4 + wid] = ssq; }
                __syncthreads();
                const float invp = 1.0f / fmaxf(sqrtf(sbuf[0] + sbuf[1] + sbuf[2] + sbuf[3]), EPS);
                const float invq = 1.0f / fmaxf(sqrtf(sbuf[4] + sbuf[5] + sbuf[6] + sbuf[7]), EPS);
                __syncthreads();
                FMA16(a0, a1, a2, a3, p0, p1, p2, p3, invp);
                FMA16(a0, a1, a2, a3, q0, q1, q2, q3, invq);
            } else if (rem == 1) {
                const float4* rp = reinterpret_cast<const float4*>(xs + (size_t)match_idx[t] * D);
                float4 p0, p1, p2, p3;
                LOAD16(p0, p1, p2, p3, rp);
                float ssp = SUMSQ16(p0, p1, p2, p3);
                ssp = wave_sum(ssp);
                if (lane == 0) sbuf[wid] = ssp;
                __syncthreads();
                const float invp = 1.0f / fmaxf(sqrtf(sbuf[0] + sbuf[1] + sbuf[2] + sbuf[3]), EPS);
                __syncthreads();
                FMA16(a0, a1, a2, a3, p0, p1, p2, p3, invp);
            }
            float s2 = SUMSQ16(a0, a1, a2, a3);
            s2 = wave_sum(s2);
            if (lane == 0) sbuf[wid] = s2;
            __syncthreads();
            if (threadIdx.x == 0) {
                float S2 = sbuf[0] + sbuf[1] + sbuf[2] + sbuf[3];
                psim = 0.5f * (S2 - (float)n);  // sum_i ||xn_i||^2 == n
            }
        }
        if (threadIdx.x == 0) {
            pos_sim[cls] = psim;
            pos_cnt[cls] = 0.5f * (float)n * (float)(n - 1);
        }
    } else if (blk < C + NNEG) {
        // ---- negative pair (0, j), inline norms ----
        const int j = blk - C + 1;
        const float4* r0 = reinterpret_cast<const float4*>(xs);
        const float4* rj = reinterpret_cast<const float4*>(xs + (size_t)j * D);
        float ss0 = 0.0f, ssj = 0.0f, d = 0.0f;
#pragma unroll
        for (int k = 0; k < 4; ++k) {
            float4 a = r0[threadIdx.x + k * 256];
            float4 b = rj[threadIdx.x + k * 256];
            ss0 += a.x * a.x + a.y * a.y + a.z * a.z + a.w * a.w;
            ssj += b.x * b.x + b.y * b.y + b.z * b.z + b.w * b.w;
            d = fmaf(a.x, b.x, fmaf(a.y, b.y, fmaf(a.z, b.z, fmaf(a.w, b.w, d))));
        }
        ss0 = wave_sum(ss0);
        ssj = wave_sum(ssj);
        d = wave_sum(d);
        if (lane == 0) {
            sbuf[wid] = ss0;
            sbuf[4 + wid] = ssj;
            sbuf[8 + wid] = d;
        }
        __syncthreads();
        if (threadIdx.x == 0) {
            float n0 = fmaxf(sqrtf(sbuf[0] + sbuf[1] + sbuf[2] + sbuf[3]), EPS);
            float nj = fmaxf(sqrtf(sbuf[4] + sbuf[5] + sbuf[6] + sbuf[7]), EPS);
            float dot = sbuf[8] + sbuf[9] + sbuf[10] + sbuf[11];
            neg_part[j - 1] = fmaxf(0.0f, dot / (n0 * nj));
        }
    } else {
        // ---- cross-entropy row (250 float4 loads, target logit from the
        //      owning thread's registers; __expf/__logf: HW transcendentals,
        //      abs err ~1e-4 << 0.169 threshold) ----
        const int row = blk - C - NNEG;
        const float4* r4 = reinterpret_cast<const float4*>(yp + (size_t)row * C);
        const int tgt = yt[row];
        float4 v = {0.0f, 0.0f, 0.0f, 0.0f};
        float m = -INFINITY;
        if (threadIdx.x < 250) {
            v = r4[threadIdx.x];
            m = fmaxf(fmaxf(v.x, v.y), fmaxf(v.z, v.w));
        }
        if (threadIdx.x == (tgt >> 2)) {
            const int c4 = tgt & 3;
            sbuf[12] = (c4 == 0) ? v.x : (c4 == 1) ? v.y : (c4 == 2) ? v.z : v.w;
        }
        m = wave_max(m);
        if (lane == 0) sbuf[wid] = m;
        __syncthreads();
        m = fmaxf(fmaxf(sbuf[0], sbuf[1]), fmaxf(sbuf[2], sbuf[3]));
        float s = 0.0f;
        if (threadIdx.x < 250) {
            s = __expf(v.x - m) + __expf(v.y - m) + __expf(v.z - m) + __expf(v.w - m);
        }
        s = wave_sum(s);
        if (lane == 0) sbuf[4 + wid] = s;  // disjoint slots: no extra barrier
        __syncthreads();
        if (threadIdx.x == 0) {
            float tot = sbuf[4] + sbuf[5] + sbuf[6] + sbuf[7];
            ce_part[row] = __logf(tot) + m - sbuf[12];
        }
    }
}

__global__ __launch_bounds__(256) void k_finalize(const float* __restrict__ ce_part,
                                                  const float* __restrict__ pos_sim,
                                                  const float* __restrict__ pos_cnt,
                                                  const float* __restrict__ neg_part,
                                                  float* __restrict__ out) {
    __shared__ float sbuf[12];
    const int lane = threadIdx.x & 63, wid = threadIdx.x >> 6;
    float s_ce = 0.0f, s_sim = 0.0f, s_cnt = 0.0f;
    // ce_part: 2048 floats = 512 float4 -> 2 rounds of 256
    const float4* ce4 = reinterpret_cast<const float4*>(ce_part);
#pragma unroll
    for (int k = 0; k < 2; ++k) {
        float4 v = ce4[threadIdx.x + k * 256];
        s_ce += v.x + v.y + v.z + v.w;
    }
    // pos_sim / pos_cnt: 1000 floats = 250 float4 -> 1 round (250 threads)
    if (threadIdx.x < 250) {
        float4 vs = reinterpret_cast<const float4*>(pos_sim)[threadIdx.x];
        float4 vc = reinterpret_cast<const float4*>(pos_cnt)[threadIdx.x];
        s_sim = vs.x + vs.y + vs.z + vs.w;
        s_cnt = vc.x + vc.y + vc.z + vc.w;
    }
    float s_neg = (threadIdx.x < NNEG) ? neg_part[threadIdx.x] : 0.0f;
    s_ce = wave_sum(s_ce);
    s_sim = wave_sum(s_sim);
    s_cnt = wave_sum(s_cnt);
    s_neg = wave_sum(s_neg);
    if (lane == 0) {
        sbuf[wid] = s_ce;
        sbuf[4 + wid] = s_sim;
        sbuf[8 + wid] = s_cnt;
    }
    __syncthreads();
    if (threadIdx.x == 0) {
        float ce = (sbuf[0] + sbuf[1] + sbuf[2] + sbuf[3]) / (float)B;
        float sim = sbuf[4] + sbuf[5] + sbuf[6] + sbuf[7];
        float cnt = sbuf[8] + sbuf[9] + sbuf[10] + sbuf[11];
        float pos = (cnt > 0.0f) ? (cnt - sim) / cnt : 0.0f;
        float neg = s_neg / (float)NNEG;  // wave 0 covers lanes 0..15
        out[0] = ce + pos + neg;
    }
}

extern "C" void kernel_launch(void* const* d_in, const int* in_sizes, int n_in,
                              void* d_out, int out_size, void* d_ws, size_t ws_size,
                              hipStream_t stream) {
    const float* xs = (const float*)d_in[0];
    const float* yp = (const float*)d_in[1];
    const int* yt = (const int*)d_in[2];
    float* out = (float*)d_out;

    float* ce_part = (float*)d_ws;
    float* pos_sim = ce_part + B;
    float* pos_cnt = pos_sim + C;
    float* neg_part = pos_cnt + C;

    k_main<<<C + NNEG + B, 256, 0, stream>>>(xs, yp, yt, ce_part, pos_sim, pos_cnt, neg_part);
    k_finalize<<<1, 256, 0, stream>>>(ce_part, pos_sim, pos_cnt, neg_part, out);
}